// Round 6
// baseline (333.187 us; speedup 1.0000x reference)
//
#include <hip/hip_runtime.h>
#include <stdint.h>

// B=512, T=256, N_EMBED=384, HEAD_SIZE=64
// Round-6: RESUBMIT of round-5 (container infra failure, experiment unrun).
// Split (R3 skeleton), attn REWRITTEN, proj/prep_w byte-identical to R3
// (single-variable experiment).
// attn v2: - wave owns the q-tile PAIR (t, 15-t) sequentially => every wave
//            does exactly 17 tile-units (was 1..16: block time = worst wave).
//          - kf loads + QK MFMAs unconditional over all 8 tiles of a chunk
//            (always in-bounds; causal mask reproduces the old -1e30 fill
//            bit-exactly) => no divergent guards, loads can batch/hoist.
//          - XCD-chunked bijective swizzle (nwg=1024) so a batch's 2 blocks
//            share one XCD L2 for its 64KB KQV.
//          - PV loop still guarded by kblks (serial Oacc chain; masked P==0).
// ws layout: Wt3 @ 0 (147456 B); KQV @ 1 MiB: per batch 49152 shorts
//            (Kf 16384 | Qf 16384 | Vf 16384), frag layouts as before.

typedef short s16x8 __attribute__((ext_vector_type(8)));
typedef float f32x4 __attribute__((ext_vector_type(4)));

#define LOG2E_OVER_8 0.18033688011112042f

__device__ inline short f2bf(float f) {
  union { float f; uint32_t u; } v; v.f = f;
  uint32_t r = (v.u + 0x7fffu + ((v.u >> 16) & 1u)) >> 16;  // RNE
  return (short)r;
}

// ---- Kernel 0: W fp32 -> bf16 fragment-ordered Wt3, fold 0.125*log2e into Wq
__global__ __launch_bounds__(256) void prep_w(const float* __restrict__ Wk,
                                              const float* __restrict__ Wq,
                                              const float* __restrict__ Wv,
                                              short* __restrict__ Wt3) {
  int idx = blockIdx.x * 256 + threadIdx.x;  // 0..73727
  int j = idx & 7;
  int lane = (idx >> 3) & 63;
  int rest = idx >> 9;          // 0..143
  int ntile = rest % 12;
  int kc = rest / 12;
  int n = ntile * 16 + (lane & 15);
  int kk = (lane >> 4) * 8 + j;
  int col = n & 63;
  int w = n >> 6;
  const float* W = (w == 0) ? Wk : (w == 1) ? Wq : Wv;
  float v = W[(kc * 32 + kk) * 64 + col];
  if (w == 1) v *= LOG2E_OVER_8;
  Wt3[idx] = f2bf(v);
}

// ---- Kernel 1: QKV projection (byte-identical to R3). grid 2048, block 256.
__global__ __launch_bounds__(256, 4) void proj(const float* __restrict__ x,
                                               const short* __restrict__ Wt3,
                                               short* __restrict__ kqv) {
  __shared__ __align__(16) short Wl[12288];  // 24KB: W dbuf; epilogue C bounce

  const int tid = threadIdx.x;
  const int wave = tid >> 6;
  const int lane = tid & 63;
  const int l15 = lane & 15;
  const int quad = lane >> 4;
  const int blk = blockIdx.x;
  const int b = blk >> 2;          // batch
  const int tb = (blk & 3) * 4;    // first 16-row tile of this block in batch
  const int t = tb + wave;         // wave's tile 0..15

  const float* xw = x + (long)b * (256 * 384) + (t * 16 + l15) * 384 + quad * 8;
  const int so = tid * 8;  // W stage slot (shorts)

  f32x4 acc[12];
#pragma unroll
  for (int nt = 0; nt < 12; ++nt) acc[nt] = (f32x4)0.0f;

  f32x4 xa0 = *(const f32x4*)(xw);
  f32x4 xa1 = *(const f32x4*)(xw + 4);
  s16x8 w0 = *(const s16x8*)(Wt3 + so);
  s16x8 w1 = *(const s16x8*)(Wt3 + so + 2048);
  s16x8 w2 = *(const s16x8*)(Wt3 + so + 4096);

#pragma unroll
  for (int kc = 0; kc < 12; ++kc) {
    short* buf = Wl + (kc & 1) * 6144;
    *(s16x8*)(buf + so) = w0;
    *(s16x8*)(buf + so + 2048) = w1;
    *(s16x8*)(buf + so + 4096) = w2;

    s16x8 af;
    af[0] = f2bf(xa0[0]); af[1] = f2bf(xa0[1]); af[2] = f2bf(xa0[2]); af[3] = f2bf(xa0[3]);
    af[4] = f2bf(xa1[0]); af[5] = f2bf(xa1[1]); af[6] = f2bf(xa1[2]); af[7] = f2bf(xa1[3]);

    __syncthreads();  // stage visible; prior-parity reads (kc-2) long done

    if (kc < 11) {
      xa0 = *(const f32x4*)(xw + (kc + 1) * 32);
      xa1 = *(const f32x4*)(xw + (kc + 1) * 32 + 4);
      w0 = *(const s16x8*)(Wt3 + (kc + 1) * 6144 + so);
      w1 = *(const s16x8*)(Wt3 + (kc + 1) * 6144 + so + 2048);
      w2 = *(const s16x8*)(Wt3 + (kc + 1) * 6144 + so + 4096);
    }

#pragma unroll
    for (int nt = 0; nt < 12; ++nt) {
      s16x8 bfv = *(const s16x8*)(buf + nt * 512 + lane * 8);
      acc[nt] = __builtin_amdgcn_mfma_f32_16x16x32_bf16(af, bfv, acc[nt], 0, 0, 0);
    }
  }
  __syncthreads();  // Wl free for epilogue bounce

  const int base_sub = tb * 1024;
#pragma unroll
  for (int nt = 0; nt < 12; ++nt) {
    const int h = (nt * 16 + l15) & 63;
    const int which = nt >> 2;
#pragma unroll
    for (int r = 0; r < 4; ++r) {
      const short v = f2bf(acc[nt][r]);
      const int row = t * 16 + quad * 4 + r;
      if (which == 2) {
        const int idx = ((row >> 5) * 4 + (h >> 4)) * 512 +
                        ((h & 15) + ((row & 31) >> 3) * 16) * 8 + (row & 7) - base_sub;
        Wl[8192 + idx] = v;
      } else {
        const int idx = ((row >> 4) * 2 + (h >> 5)) * 512 +
                        ((row & 15) + ((h & 31) >> 3) * 16) * 8 + (h & 7) - base_sub;
        Wl[which * 4096 + idx] = v;
      }
    }
  }
  __syncthreads();  // V slots interleave rows across waves

  short* dstK = kqv + (long)b * 49152 + base_sub;
  short* dstQ = dstK + 16384;
  short* dstV = dstK + 32768;
  *(s16x8*)(dstK + so)        = *(const s16x8*)(Wl + so);
  *(s16x8*)(dstK + 2048 + so) = *(const s16x8*)(Wl + 2048 + so);
  *(s16x8*)(dstQ + so)        = *(const s16x8*)(Wl + 4096 + so);
  *(s16x8*)(dstQ + 2048 + so) = *(const s16x8*)(Wl + 6144 + so);
  *(s16x8*)(dstV + so)        = *(const s16x8*)(Wl + 8192 + so);
  *(s16x8*)(dstV + 2048 + so) = *(const s16x8*)(Wl + 10240 + so);
}

// ---- Kernel 2: causal flash attention v2. grid 1024, block 256 (4 waves).
// Wave = q-tile pair (tpair, 15-tpair): exactly 17 tile-units per wave.
__global__ __launch_bounds__(256, 4) void attn(const short* __restrict__ kqv,
                                               float* __restrict__ out) {
  __shared__ __align__(16) short P[8192];  // 4 waves x 2048 shorts (A-frag)

  const int tid = threadIdx.x;
  const int wave = tid >> 6;
  const int lane = tid & 63;
  const int l15 = lane & 15;
  const int quad = lane >> 4;

  // XCD-chunked bijective swizzle (nwg=1024, 1024%8==0): dispatch d -> lb
  const int d = blockIdx.x;
  const int lb = (d & 7) * 128 + (d >> 3);
  const int b = lb >> 1;
  const int tpair = (lb & 1) * 4 + wave;  // 0..7

  const short* Kg = kqv + (long)b * 49152;
  const short* Qg = Kg + 16384;
  const short* Vg = Kg + 32768;
  short* Pw = P + wave * 2048;

#pragma unroll
  for (int pi = 0; pi < 2; ++pi) {
    const int t = pi ? (15 - tpair) : tpair;
    const int q0 = t * 16;

    s16x8 qf0 = *(const s16x8*)(Qg + (t * 2 + 0) * 512 + lane * 8);
    s16x8 qf1 = *(const s16x8*)(Qg + (t * 2 + 1) * 512 + lane * 8);

    f32x4 Oacc[4];
#pragma unroll
    for (int n = 0; n < 4; ++n) Oacc[n] = (f32x4)0.0f;
    float mrow[4] = {-1e30f, -1e30f, -1e30f, -1e30f};
    float lrow[4] = {0.f, 0.f, 0.f, 0.f};

    const int nb = (t >= 8) ? 2 : 1;
    for (int cb = 0; cb < nb; ++cb) {
      const int st0 = cb * 8;
      const bool last = (cb == nb - 1);
      const int nuse = last ? (t - cb * 8 + 1) : 8;

      // Unconditional loads+MFMAs (always in-bounds: st0+n <= 15). For masked
      // tiles the causal test s_abs>q_abs always holds => S=-1e30, bit-equal
      // to the old guarded fill.
      float S[8][4];
#pragma unroll
      for (int n = 0; n < 8; ++n) {
        s16x8 kf0 = *(const s16x8*)(Kg + ((st0 + n) * 2 + 0) * 512 + lane * 8);
        s16x8 kf1 = *(const s16x8*)(Kg + ((st0 + n) * 2 + 1) * 512 + lane * 8);
        f32x4 z = (f32x4)0.0f;
        z = __builtin_amdgcn_mfma_f32_16x16x32_bf16(qf0, kf0, z, 0, 0, 0);
        z = __builtin_amdgcn_mfma_f32_16x16x32_bf16(qf1, kf1, z, 0, 0, 0);
        if (last) {
          const int s_abs = cb * 128 + n * 16 + l15;
#pragma unroll
          for (int r = 0; r < 4; ++r) {
            const int q_abs = q0 + quad * 4 + r;
            S[n][r] = (s_abs > q_abs) ? -1e30f : z[r];
          }
        } else {
#pragma unroll
          for (int r = 0; r < 4; ++r) S[n][r] = z[r];
        }
      }

      // online softmax (base-2); row r lives in the 16 lanes of this quad
      float alpha[4];
#pragma unroll
      for (int r = 0; r < 4; ++r) {
        float mx = S[0][r];
#pragma unroll
        for (int n = 1; n < 8; ++n) mx = fmaxf(mx, S[n][r]);
        mx = fmaxf(mx, __shfl_xor(mx, 1));
        mx = fmaxf(mx, __shfl_xor(mx, 2));
        mx = fmaxf(mx, __shfl_xor(mx, 4));
        mx = fmaxf(mx, __shfl_xor(mx, 8));
        float mnew = fmaxf(mrow[r], mx);
        alpha[r] = __builtin_amdgcn_exp2f(mrow[r] - mnew);
        mrow[r] = mnew;
      }
      float rs[4] = {0.f, 0.f, 0.f, 0.f};
#pragma unroll
      for (int n = 0; n < 8; ++n) {
#pragma unroll
        for (int r = 0; r < 4; ++r) {
          float p = __builtin_amdgcn_exp2f(S[n][r] - mrow[r]);  // masked -> 0
          rs[r] += p;
          Pw[(n >> 1) * 512 + ((quad * 4 + r) + ((n & 1) * 2 + (l15 >> 3)) * 16) * 8 + (l15 & 7)] = f2bf(p);
        }
      }
#pragma unroll
      for (int r = 0; r < 4; ++r) {
        float s = rs[r];
        s += __shfl_xor(s, 1);
        s += __shfl_xor(s, 2);
        s += __shfl_xor(s, 4);
        s += __shfl_xor(s, 8);
        lrow[r] = lrow[r] * alpha[r] + s;
#pragma unroll
        for (int n = 0; n < 4; ++n) Oacc[n][r] *= alpha[r];
      }
      // P strip is wave-private: drain DS writes before re-reading (no barrier)
      asm volatile("s_waitcnt lgkmcnt(0)" ::: "memory");

      // O += P V over the live 32-s blocks (masked P is exactly 0, so the
      // guard only skips provably-zero contributions)
      const int kblks = (nuse + 1) >> 1;
      for (int sb = 0; sb < kblks; ++sb) {
        s16x8 pf = *(const s16x8*)(Pw + sb * 512 + lane * 8);
#pragma unroll
        for (int n2 = 0; n2 < 4; ++n2) {
          s16x8 vfv = *(const s16x8*)(Vg + ((cb * 4 + sb) * 4 + n2) * 512 + lane * 8);
          Oacc[n2] = __builtin_amdgcn_mfma_f32_16x16x32_bf16(pf, vfv, Oacc[n2], 0, 0, 0);
        }
      }
    }

    float inv[4];
#pragma unroll
    for (int r = 0; r < 4; ++r) inv[r] = 1.0f / lrow[r];
    float* ob = out + ((long)b * 256 + q0 + quad * 4) * 64;
#pragma unroll
    for (int n = 0; n < 4; ++n)
#pragma unroll
      for (int r = 0; r < 4; ++r)
        ob[r * 64 + n * 16 + l15] = Oacc[n][r] * inv[r];
  }
}

extern "C" void kernel_launch(void* const* d_in, const int* in_sizes, int n_in,
                              void* d_out, int out_size, void* d_ws, size_t ws_size,
                              hipStream_t stream) {
  const float* x = (const float*)d_in[0];
  const float* Wk = (const float*)d_in[1];
  const float* Wq = (const float*)d_in[2];
  const float* Wv = (const float*)d_in[3];
  float* out = (float*)d_out;
  short* Wt3 = (short*)d_ws;                        // 147456 B @ ws+0
  short* kqv = (short*)d_ws + (1 << 20) / 2;        // 50.3 MB @ ws+1MiB

  prep_w<<<288, 256, 0, stream>>>(Wk, Wq, Wv, Wt3);
  proj<<<2048, 256, 0, stream>>>(x, Wt3, kqv);
  attn<<<1024, 256, 0, stream>>>(kqv, out);
}